// Round 6
// baseline (226.847 us; speedup 1.0000x reference)
//
#include <hip/hip_runtime.h>
#include <hip/hip_fp16.h>

#define DIM 64
#define NEG_SLOPE 0.01f
#define BKT 256          // nodes per bucket (LDS hist granularity in k_bucket)
#define TILEP 4096       // symmetric PAIRS per hist/place tile (= 8192 records)
#define RECS (TILEP * 2) // records per tile
#define STILE 2048       // scan1 tile: 256 thr x 8

typedef unsigned u32;
typedef unsigned short u16;
typedef unsigned char u8;

// ---------------------------------------------------------------------------
// Round 14: convs were latency-bound on per-wave serial gather chains.
// (a) Degree-sorted row order: waves process 8 equal-degree rows, so the
//     chunk loop runs mean-degree iterations, not max-of-8 (Poisson(6):
//     73% of waves ran >=2 chains; now ~10%). Degree hist folded into
//     k_bucket (it already has per-node degree in LDS); + tiny 256-bin
//     scan + counting-sort order kernel.
// (b) Branch-free chunks: invalid lanes carry u=0 -> cx=0, cy=0 (weight
//     exactly 0, dummy load hits cached row 0), so all guards are dropped:
//     8 shfl + 8 independent loads + 8 FMAs, one waitcnt per chunk.
// Build pipeline unchanged from R12/R13.
// ---------------------------------------------------------------------------

__global__ void k_norm_hist(const float* __restrict__ emb,
                            __half* __restrict__ x0h,
                            const int* __restrict__ p,
                            u32* __restrict__ mat,
                            int N, int E, int rb, int B, int nblkE) {
    int t = threadIdx.x;
    if ((int)blockIdx.x < rb) {
        // L2-normalize: 16 lanes/row, 4 rows/wave, 8 waves -> 32 rows/block
        int lane = t & 63;
        int row  = blockIdx.x * 32 + (t >> 6) * 4 + (lane >> 4);
        int l16  = lane & 15;
        if (row >= N) return;
        float4 v = *(const float4*)(emb + (size_t)row * DIM + l16 * 4);
        float s = v.x * v.x + v.y * v.y + v.z * v.z + v.w * v.w;
        #pragma unroll
        for (int m = 1; m < 16; m <<= 1) s += __shfl_xor(s, m, 64);
        float inv = 1.0f / fmaxf(sqrtf(s), 1e-12f);
        union { uint2 u; __half2 h[2]; } pk;
        pk.h[0] = __floats2half2_rn(v.x * inv, v.y * inv);
        pk.h[1] = __floats2half2_rn(v.z * inv, v.w * inv);
        *(uint2*)(x0h + (size_t)row * DIM + l16 * 4) = pk.u;
    } else {
        __shared__ u32 hist[800];           // B = 782 bins
        int blk = blockIdx.x - rb;
        for (int i = t; i < B; i += 512) hist[i] = 0;
        __syncthreads();
        int base = blk * TILEP;
        #pragma unroll
        for (int k = 0; k < TILEP / 512; k++) {
            int pe = base + k * 512 + t;
            if (pe < E) {
                int a = p[pe];
                int b = p[pe + E];
                atomicAdd(&hist[(u32)b >> 8], 1u);
                atomicAdd(&hist[(u32)a >> 8], 1u);
            }
        }
        __syncthreads();
        for (int i = t; i < B; i += 512) mat[(size_t)i * nblkE + blk] = hist[i];
    }
}

__global__ void k_scan1(const u32* __restrict__ in, u32* __restrict__ out,
                        u32* __restrict__ bsum, int M) {
    __shared__ u32 sdata[256];
    int t = threadIdx.x;
    int base = blockIdx.x * STILE + t * 8;
    u32 v[8]; u32 tsum = 0;
    #pragma unroll
    for (int k = 0; k < 8; k++) {
        int i = base + k;
        v[k] = (i < M) ? in[i] : 0u;
        tsum += v[k];
    }
    sdata[t] = tsum;
    __syncthreads();
    for (int off = 1; off < 256; off <<= 1) {
        u32 x = (t >= off) ? sdata[t - off] : 0u;
        __syncthreads();
        sdata[t] += x;
        __syncthreads();
    }
    u32 run = sdata[t] - tsum;
    if (t == 255) bsum[blockIdx.x] = sdata[255];
    #pragma unroll
    for (int k = 0; k < 8; k++) {
        int i = base + k;
        if (i < M) out[i] = run;
        run += v[k];
    }
}

// fold block offsets into mscan; block 0 also zeroes the degree histogram
__global__ void k_scanfix(u32* __restrict__ mscan,
                          const u32* __restrict__ bsum,
                          u32* __restrict__ dhist, int nb, int M) {
    __shared__ u32 sdata[256];
    __shared__ u32 sexcl[256];
    int t = threadIdx.x;
    if (blockIdx.x == 0) dhist[t] = 0;
    u32 v = (t < nb) ? bsum[t] : 0u;
    sdata[t] = v;
    __syncthreads();
    for (int off = 1; off < 256; off <<= 1) {
        u32 x = (t >= off) ? sdata[t - off] : 0u;
        __syncthreads();
        sdata[t] += x;
        __syncthreads();
    }
    sexcl[t] = sdata[t] - v;
    __syncthreads();
    int i = blockIdx.x * 256 + t;
    if (i < M) mscan[i] += sexcl[i >> 11];
}

// LDS tile sort + coalesced run write-out. ~94KB LDS, 1 block/CU.
__global__ __launch_bounds__(512, 1)
void k_place(const int* __restrict__ p, const float* __restrict__ w,
             const u32* __restrict__ mscan,
             u32* __restrict__ pay, u8* __restrict__ loc8,
             int E, int nblkE, int B) {
    __shared__ u32 sPay[RECS];    // 32KB
    __shared__ u32 sMeta[RECS];   // 32KB (= dst node id; bin=>>8, loc=&255)
    __shared__ u16 sPerm[RECS];   // 16KB
    __shared__ u32 hist[1024];    // counts -> (rezeroed) cursors
    __shared__ u32 sstart[1024];
    __shared__ u32 delta[1024];
    __shared__ u32 sdata[512];

    int blk = blockIdx.x;
    int t = threadIdx.x;
    int base = blk * TILEP;
    int rem = E - base;                       // pairs in this tile
    int vlim = rem * 2; if (vlim > RECS) vlim = RECS;

    hist[t] = 0; hist[t + 512] = 0;
    __syncthreads();

    // pass A: stage records + count bins
    #pragma unroll
    for (int k = 0; k < TILEP / 512; k++) {
        int pe = base + k * 512 + t;
        if (pe < E) {
            int a = p[pe];
            int b = p[pe + E];
            float wf = w[pe];
            float wb = w[pe + E];
            u32 wf14 = (u32)(wf * 16384.0f + 0.5f); if (wf14 > 16383u) wf14 = 16383u;
            u32 wb14 = (u32)(wb * 16384.0f + 0.5f); if (wb14 > 16383u) wb14 = 16383u;
            int li = (k * 512 + t) * 2;
            sPay[li]      = ((u32)a << 14) | wf14;   // fwd record: dst = b
            sMeta[li]     = (u32)b;
            sPay[li + 1]  = ((u32)b << 14) | wb14;   // bwd record: dst = a
            sMeta[li + 1] = (u32)a;
            atomicAdd(&hist[(u32)b >> 8], 1u);
            atomicAdd(&hist[(u32)a >> 8], 1u);
        }
    }
    __syncthreads();

    // scan 1024 bins (2 per thread) -> sstart (exclusive)
    u32 a0 = hist[2 * t], a1 = hist[2 * t + 1];
    u32 tsum = a0 + a1;
    sdata[t] = tsum;
    __syncthreads();
    for (int off = 1; off < 512; off <<= 1) {
        u32 x = (t >= off) ? sdata[t - off] : 0u;
        __syncthreads();
        sdata[t] += x;
        __syncthreads();
    }
    u32 texcl = sdata[t] - tsum;
    sstart[2 * t]     = texcl;
    sstart[2 * t + 1] = texcl + a0;
    __syncthreads();

    // rezero hist (becomes rank cursor) + load this tile's mscan column
    hist[t] = 0; hist[t + 512] = 0;
    for (int i = t; i < B; i += 512)
        delta[i] = mscan[(size_t)i * nblkE + blk] - sstart[i];
    __syncthreads();

    // pass B: build permutation (staging order sorted by bin)
    #pragma unroll
    for (int k = 0; k < RECS / 512; k++) {
        int li = k * 512 + t;
        if (li < vlim) {
            u32 bin = sMeta[li] >> 8;
            u32 r = atomicAdd(&hist[bin], 1u);
            sPerm[sstart[bin] + r] = (u16)li;
        }
    }
    __syncthreads();

    // pass C: write out in sorted order; consecutive j -> consecutive gslot
    #pragma unroll
    for (int k = 0; k < RECS / 512; k++) {
        int j = k * 512 + t;
        if (j < vlim) {
            int li = sPerm[j];
            u32 pv = sPay[li];
            u32 mt = sMeta[li];
            u32 gs = (u32)j + delta[mt >> 8];   // = mscan base + rank (u32 wrap ok)
            pay[gs]  = pv;
            loc8[gs] = (u8)(mt & 255u);
        }
    }
}

__global__ void k_bucket(const u32* __restrict__ pay,
                         const u8* __restrict__ loc8,
                         const u32* __restrict__ mscan,
                         u32* __restrict__ row_ptr,
                         u32* __restrict__ colw,
                         u32* __restrict__ dhist,
                         int N, int E, int B, int nblkE) {
    __shared__ u32 hist[BKT];
    __shared__ u32 excl[BKT];
    __shared__ u32 sdata[256];
    __shared__ u32 dh[256];
    int b = blockIdx.x;
    int t = threadIdx.x;
    int node0 = b * BKT;
    int nnodes = N - node0; if (nnodes > BKT) nnodes = BKT;
    size_t flat0 = (size_t)b * nblkE;
    u32 seg_s = mscan[flat0];
    u32 seg_e = (b + 1 < B) ? mscan[flat0 + nblkE] : (u32)(2 * E);
    hist[t] = 0;
    dh[t] = 0;
    __syncthreads();
    for (u32 j = seg_s + t; j < seg_e; j += 256)
        atomicAdd(&hist[loc8[j]], 1u);
    __syncthreads();
    u32 tsum = hist[t];                 // = degree of node node0+t
    if (t < nnodes) atomicAdd(&dh[tsum > 255u ? 255u : tsum], 1u);
    sdata[t] = tsum;
    __syncthreads();
    for (int off = 1; off < 256; off <<= 1) {
        u32 x = (t >= off) ? sdata[t - off] : 0u;
        __syncthreads();
        sdata[t] += x;
        __syncthreads();
    }
    u32 texcl = sdata[t] - tsum;
    excl[t] = texcl;
    if (t < nnodes) row_ptr[node0 + t] = seg_s + texcl;
    if (b == 0 && t == 0) row_ptr[N] = (u32)(2 * E);
    __syncthreads();
    if (dh[t]) atomicAdd(&dhist[t], dh[t]);    // flush degree histogram
    for (u32 j = seg_s + t; j < seg_e; j += 256) {
        u32 loc = loc8[j];
        u32 pos = atomicAdd(&excl[loc], 1u);
        colw[seg_s + pos] = pay[j];
    }
}

// exclusive scan of the 256-bin degree histogram -> global cursors
__global__ void k_dscan(const u32* __restrict__ dhist, u32* __restrict__ dcur) {
    __shared__ u32 sdata[256];
    int t = threadIdx.x;
    u32 v = dhist[t];
    sdata[t] = v;
    __syncthreads();
    for (int off = 1; off < 256; off <<= 1) {
        u32 x = (t >= off) ? sdata[t - off] : 0u;
        __syncthreads();
        sdata[t] += x;
        __syncthreads();
    }
    dcur[t] = sdata[t] - v;
}

// counting-sort nodes by degree: order[] = node ids grouped by degree
__global__ void k_dorder(const u32* __restrict__ rp, u32* __restrict__ dcur,
                         u32* __restrict__ order, int N) {
    __shared__ u32 lh[256];
    __shared__ u32 lbase[256];
    __shared__ u32 lcur[256];
    int t = threadIdx.x;
    lh[t] = 0;
    __syncthreads();
    int base = blockIdx.x * 2048;
    u32 degv[8];
    #pragma unroll
    for (int k = 0; k < 8; k++) {
        int i = base + k * 256 + t;
        u32 d = 0;
        if (i < N) {
            d = rp[i + 1] - rp[i];
            if (d > 255u) d = 255u;
            atomicAdd(&lh[d], 1u);
        }
        degv[k] = d;
    }
    __syncthreads();
    u32 c = lh[t];
    lbase[t] = c ? atomicAdd(&dcur[t], c) : 0u;
    lcur[t] = 0;
    __syncthreads();
    #pragma unroll
    for (int k = 0; k < 8; k++) {
        int i = base + k * 256 + t;
        if (i < N) {
            u32 d = degv[k];
            u32 r = atomicAdd(&lcur[d], 1u);
            order[lbase[d] + r] = (u32)i;
        }
    }
}

// --- conv: 8 rows/wave, 8 lanes/row, lane covers dims [sub*8, sub*8+8) ----

__device__ __forceinline__ void fma8(const uint4& q, float wj, float acc[8]) {
    const __half2* hp = (const __half2*)&q;
    #pragma unroll
    for (int k = 0; k < 4; k++) {
        float2 f = __half22float2(hp[k]);
        acc[2 * k]     += f.x * wj;
        acc[2 * k + 1] += f.y * wj;
    }
}

// branch-free: lanes with sub>=m carry u=0 -> cx=0 (cached row 0), cy=0
// (exact zero weight), so all 8 loads+FMAs run unconditionally.
__device__ __forceinline__ void gather8(const __half* __restrict__ x,
                                        const u32* __restrict__ colw,
                                        u32 s, u32 e, int g, int sub,
                                        float acc[8]) {
    int lb = g << 3;
    for (u32 base = s; base < e; base += 8) {
        int m = (int)(e - base); if (m > 8) m = 8;
        u32 u = (sub < m) ? colw[base + sub] : 0u;
        int   cx = (int)(u >> 14);
        float cy = (float)(u & 16383u) * (1.0f / 16384.0f);
        int s0 = __shfl(cx, lb + 0, 64), s1 = __shfl(cx, lb + 1, 64);
        int s2 = __shfl(cx, lb + 2, 64), s3 = __shfl(cx, lb + 3, 64);
        int s4 = __shfl(cx, lb + 4, 64), s5 = __shfl(cx, lb + 5, 64);
        int s6 = __shfl(cx, lb + 6, 64), s7 = __shfl(cx, lb + 7, 64);
        uint4 q0 = *(const uint4*)(x + (size_t)s0 * DIM + sub * 8);
        uint4 q1 = *(const uint4*)(x + (size_t)s1 * DIM + sub * 8);
        uint4 q2 = *(const uint4*)(x + (size_t)s2 * DIM + sub * 8);
        uint4 q3 = *(const uint4*)(x + (size_t)s3 * DIM + sub * 8);
        uint4 q4 = *(const uint4*)(x + (size_t)s4 * DIM + sub * 8);
        uint4 q5 = *(const uint4*)(x + (size_t)s5 * DIM + sub * 8);
        uint4 q6 = *(const uint4*)(x + (size_t)s6 * DIM + sub * 8);
        uint4 q7 = *(const uint4*)(x + (size_t)s7 * DIM + sub * 8);
        float w0 = __shfl(cy, lb + 0, 64), w1 = __shfl(cy, lb + 1, 64);
        float w2 = __shfl(cy, lb + 2, 64), w3 = __shfl(cy, lb + 3, 64);
        float w4 = __shfl(cy, lb + 4, 64), w5 = __shfl(cy, lb + 5, 64);
        float w6 = __shfl(cy, lb + 6, 64), w7 = __shfl(cy, lb + 7, 64);
        fma8(q0, w0, acc); fma8(q1, w1, acc);
        fma8(q2, w2, acc); fma8(q3, w3, acc);
        fma8(q4, w4, acc); fma8(q5, w5, acc);
        fma8(q6, w6, acc); fma8(q7, w7, acc);
    }
}

__global__ void k_conv1(const __half* __restrict__ x0h,
                        const u32* __restrict__ row_ptr,
                        const u32* __restrict__ colw,
                        const u32* __restrict__ order,
                        __half* __restrict__ x1h, int N) {
    int wave = (blockIdx.x * 256 + threadIdx.x) >> 6;
    int g    = (threadIdx.x >> 3) & 7;
    int sub  = threadIdx.x & 7;
    int idx  = wave * 8 + g;
    if (idx >= N) return;
    int row = (int)order[idx];
    u32 s = row_ptr[row], e = row_ptr[row + 1];
    float acc[8] = {0, 0, 0, 0, 0, 0, 0, 0};
    gather8(x0h, colw, s, e, g, sub, acc);
    float rdeno = 1.0f / fmaxf((float)(e - s), 1.0f);
    __half2 hv[4];
    #pragma unroll
    for (int k = 0; k < 4; k++) {
        float v0 = acc[2 * k] * rdeno;
        float v1 = acc[2 * k + 1] * rdeno;
        v0 = (v0 >= 0.0f) ? v0 : NEG_SLOPE * v0;
        v1 = (v1 >= 0.0f) ? v1 : NEG_SLOPE * v1;
        hv[k] = __floats2half2_rn(v0, v1);
    }
    *(uint4*)(x1h + (size_t)row * DIM + sub * 8) = *(const uint4*)hv;
}

__global__ void k_conv2(const __half* __restrict__ x0h,
                        const __half* __restrict__ x1h,
                        const u32* __restrict__ row_ptr,
                        const u32* __restrict__ colw,
                        const u32* __restrict__ order,
                        float* __restrict__ out, int N) {
    int wave = (blockIdx.x * 256 + threadIdx.x) >> 6;
    int g    = (threadIdx.x >> 3) & 7;
    int sub  = threadIdx.x & 7;
    int idx  = wave * 8 + g;
    if (idx >= N) return;
    int row = (int)order[idx];
    u32 s = row_ptr[row], e = row_ptr[row + 1];
    // hoist own-row loads so they overlap the gather latency
    uint4 q0 = *(const uint4*)(x0h + (size_t)row * DIM + sub * 8);
    uint4 q1 = *(const uint4*)(x1h + (size_t)row * DIM + sub * 8);
    float acc[8] = {0, 0, 0, 0, 0, 0, 0, 0};
    gather8(x1h, colw, s, e, g, sub, acc);
    float rdeno = 1.0f / fmaxf((float)(e - s), 1.0f);
    const __half2* h0 = (const __half2*)&q0;
    const __half2* h1 = (const __half2*)&q1;
    float r[8];
    #pragma unroll
    for (int k = 0; k < 4; k++) {
        float2 a = __half22float2(h0[k]);
        float2 b = __half22float2(h1[k]);
        float x2a = acc[2 * k] * rdeno;
        float x2b = acc[2 * k + 1] * rdeno;
        x2a = (x2a >= 0.0f) ? x2a : NEG_SLOPE * x2a;
        x2b = (x2b >= 0.0f) ? x2b : NEG_SLOPE * x2b;
        r[2 * k]     = a.x + b.x + x2a;
        r[2 * k + 1] = a.y + b.y + x2b;
    }
    float* op = out + (size_t)row * DIM + sub * 8;
    *(float4*)(op)     = make_float4(r[0], r[1], r[2], r[3]);
    *(float4*)(op + 4) = make_float4(r[4], r[5], r[6], r[7]);
}

static inline size_t align16(size_t x) { return (x + 15) & ~(size_t)15; }

extern "C" void kernel_launch(void* const* d_in, const int* in_sizes, int n_in,
                              void* d_out, int out_size, void* d_ws, size_t ws_size,
                              hipStream_t stream) {
    const int N = in_sizes[0] / DIM;      // 200000
    const int E = in_sizes[1] / 2;        // 600000

    const float* emb = (const float*)d_in[0];
    const int*   ei  = (const int*)d_in[1];
    const float* w   = (const float*)d_in[2];
    float*       out = (float*)d_out;

    const int B     = (N + BKT - 1) / BKT;          // 782 buckets
    const int nblkE = (E + TILEP - 1) / TILEP;      // 147 pair tiles
    const int M     = B * nblkE;                    // 114,954
    const int nb1   = (M + STILE - 1) / STILE;      // 57 (<=256)
    const int rb    = (N + 31) / 32;                // 6250 norm blocks (512 thr)
    const int cvb   = (N + 31) / 32;                // conv blocks: 32 rows/block
    const int ob    = (N + 2047) / 2048;            // 98 dorder blocks

    char* ws = (char*)d_ws;
    size_t off = 0;
    __half* x0h    = (__half*)(ws + off); off += align16((size_t)N * DIM * 2);
    __half* x1h    = (__half*)(ws + off); off += align16((size_t)N * DIM * 2);
    u32*    pay    = (u32*)(ws + off);    off += align16((size_t)2 * E * 4);
    u8*     loc8   = (u8*)(ws + off);     off += align16((size_t)2 * E);
    u32*    colw   = (u32*)(ws + off);    off += align16((size_t)2 * E * 4);
    u32*    mat    = (u32*)(ws + off);    off += align16((size_t)M * 4);
    u32*    mscan  = (u32*)(ws + off);    off += align16((size_t)M * 4);
    u32*    row_ptr= (u32*)(ws + off);    off += align16((size_t)(N + 1) * 4);
    u32*    bsum   = (u32*)(ws + off);    off += align16(256 * 4);
    u32*    dhist  = (u32*)(ws + off);    off += align16(256 * 4);
    u32*    dcur   = (u32*)(ws + off);    off += align16(256 * 4);
    u32*    order  = (u32*)(ws + off);    off += align16((size_t)N * 4);

    k_norm_hist<<<rb + nblkE, 512, 0, stream>>>(emb, x0h, ei, mat, N, E, rb, B, nblkE);
    k_scan1  <<<nb1, 256, 0, stream>>>(mat, mscan, bsum, M);
    k_scanfix<<<(M + 255) / 256, 256, 0, stream>>>(mscan, bsum, dhist, nb1, M);
    k_place  <<<nblkE, 512, 0, stream>>>(ei, w, mscan, pay, loc8, E, nblkE, B);
    k_bucket <<<B, 256, 0, stream>>>(pay, loc8, mscan, row_ptr, colw, dhist, N, E, B, nblkE);
    k_dscan  <<<1, 256, 0, stream>>>(dhist, dcur);
    k_dorder <<<ob, 256, 0, stream>>>(row_ptr, dcur, order, N);

    k_conv1<<<cvb, 256, 0, stream>>>(x0h, row_ptr, colw, order, x1h, N);
    k_conv2<<<cvb, 256, 0, stream>>>(x0h, x1h, row_ptr, colw, order, out, N);
}

// Round 7
// 220.547 us; speedup vs baseline: 1.0286x; 1.0286x over previous
//
#include <hip/hip_runtime.h>
#include <hip/hip_fp16.h>

#define DIM 64
#define NEG_SLOPE 0.01f
#define BKT 256          // nodes per bucket (LDS hist granularity in k_bucket)
#define TILEP 4096       // symmetric PAIRS per hist/place tile (= 8192 records)
#define RECS (TILEP * 2) // records per tile
#define STILE 2048       // scan1 tile: 256 thr x 8

typedef unsigned u32;
typedef unsigned short u16;
typedef unsigned char u8;

// ---------------------------------------------------------------------------
// Round 15: R14's degree sort REGRESSED (FETCH +11MB from scattered row
// access; occupancy down; +6us of sort kernels) — reverted. R13's real
// limiter is MLP per wave (exec-mask already handles degree divergence).
// Fix: each 8-lane group now owns TWO ADJACENT rows (wave = 16 consecutive
// rows -> locality preserved), chunks processed in lockstep with
// interleaved 4+4 branch-free load batches -> ~2x outstanding loads/CU.
// Dummy lanes carry u=0 -> exact-zero FMA vs cached row 0 (numerics
// unchanged). Build pipeline = R12/R13 exactly.
// ---------------------------------------------------------------------------

__global__ void k_norm_hist(const float* __restrict__ emb,
                            __half* __restrict__ x0h,
                            const int* __restrict__ p,
                            u32* __restrict__ mat,
                            int N, int E, int rb, int B, int nblkE) {
    int t = threadIdx.x;
    if ((int)blockIdx.x < rb) {
        // L2-normalize: 16 lanes/row, 4 rows/wave, 8 waves -> 32 rows/block
        int lane = t & 63;
        int row  = blockIdx.x * 32 + (t >> 6) * 4 + (lane >> 4);
        int l16  = lane & 15;
        if (row >= N) return;
        float4 v = *(const float4*)(emb + (size_t)row * DIM + l16 * 4);
        float s = v.x * v.x + v.y * v.y + v.z * v.z + v.w * v.w;
        #pragma unroll
        for (int m = 1; m < 16; m <<= 1) s += __shfl_xor(s, m, 64);
        float inv = 1.0f / fmaxf(sqrtf(s), 1e-12f);
        union { uint2 u; __half2 h[2]; } pk;
        pk.h[0] = __floats2half2_rn(v.x * inv, v.y * inv);
        pk.h[1] = __floats2half2_rn(v.z * inv, v.w * inv);
        *(uint2*)(x0h + (size_t)row * DIM + l16 * 4) = pk.u;
    } else {
        __shared__ u32 hist[800];           // B = 782 bins
        int blk = blockIdx.x - rb;
        for (int i = t; i < B; i += 512) hist[i] = 0;
        __syncthreads();
        int base = blk * TILEP;
        #pragma unroll
        for (int k = 0; k < TILEP / 512; k++) {
            int pe = base + k * 512 + t;
            if (pe < E) {
                int a = p[pe];
                int b = p[pe + E];
                atomicAdd(&hist[(u32)b >> 8], 1u);
                atomicAdd(&hist[(u32)a >> 8], 1u);
            }
        }
        __syncthreads();
        for (int i = t; i < B; i += 512) mat[(size_t)i * nblkE + blk] = hist[i];
    }
}

__global__ void k_scan1(const u32* __restrict__ in, u32* __restrict__ out,
                        u32* __restrict__ bsum, int M) {
    __shared__ u32 sdata[256];
    int t = threadIdx.x;
    int base = blockIdx.x * STILE + t * 8;
    u32 v[8]; u32 tsum = 0;
    #pragma unroll
    for (int k = 0; k < 8; k++) {
        int i = base + k;
        v[k] = (i < M) ? in[i] : 0u;
        tsum += v[k];
    }
    sdata[t] = tsum;
    __syncthreads();
    for (int off = 1; off < 256; off <<= 1) {
        u32 x = (t >= off) ? sdata[t - off] : 0u;
        __syncthreads();
        sdata[t] += x;
        __syncthreads();
    }
    u32 run = sdata[t] - tsum;
    if (t == 255) bsum[blockIdx.x] = sdata[255];
    #pragma unroll
    for (int k = 0; k < 8; k++) {
        int i = base + k;
        if (i < M) out[i] = run;
        run += v[k];
    }
}

// fold block offsets into mscan; each block re-scans bsum (nb<=256) in LDS
__global__ void k_scanfix(u32* __restrict__ mscan,
                          const u32* __restrict__ bsum, int nb, int M) {
    __shared__ u32 sdata[256];
    __shared__ u32 sexcl[256];
    int t = threadIdx.x;
    u32 v = (t < nb) ? bsum[t] : 0u;
    sdata[t] = v;
    __syncthreads();
    for (int off = 1; off < 256; off <<= 1) {
        u32 x = (t >= off) ? sdata[t - off] : 0u;
        __syncthreads();
        sdata[t] += x;
        __syncthreads();
    }
    sexcl[t] = sdata[t] - v;
    __syncthreads();
    int i = blockIdx.x * 256 + t;
    if (i < M) mscan[i] += sexcl[i >> 11];
}

// LDS tile sort + coalesced run write-out. ~94KB LDS, 1 block/CU.
__global__ __launch_bounds__(512, 1)
void k_place(const int* __restrict__ p, const float* __restrict__ w,
             const u32* __restrict__ mscan,
             u32* __restrict__ pay, u8* __restrict__ loc8,
             int E, int nblkE, int B) {
    __shared__ u32 sPay[RECS];    // 32KB
    __shared__ u32 sMeta[RECS];   // 32KB (= dst node id; bin=>>8, loc=&255)
    __shared__ u16 sPerm[RECS];   // 16KB
    __shared__ u32 hist[1024];    // counts -> (rezeroed) cursors
    __shared__ u32 sstart[1024];
    __shared__ u32 delta[1024];
    __shared__ u32 sdata[512];

    int blk = blockIdx.x;
    int t = threadIdx.x;
    int base = blk * TILEP;
    int rem = E - base;                       // pairs in this tile
    int vlim = rem * 2; if (vlim > RECS) vlim = RECS;

    hist[t] = 0; hist[t + 512] = 0;
    __syncthreads();

    // pass A: stage records + count bins
    #pragma unroll
    for (int k = 0; k < TILEP / 512; k++) {
        int pe = base + k * 512 + t;
        if (pe < E) {
            int a = p[pe];
            int b = p[pe + E];
            float wf = w[pe];
            float wb = w[pe + E];
            u32 wf14 = (u32)(wf * 16384.0f + 0.5f); if (wf14 > 16383u) wf14 = 16383u;
            u32 wb14 = (u32)(wb * 16384.0f + 0.5f); if (wb14 > 16383u) wb14 = 16383u;
            int li = (k * 512 + t) * 2;
            sPay[li]      = ((u32)a << 14) | wf14;   // fwd record: dst = b
            sMeta[li]     = (u32)b;
            sPay[li + 1]  = ((u32)b << 14) | wb14;   // bwd record: dst = a
            sMeta[li + 1] = (u32)a;
            atomicAdd(&hist[(u32)b >> 8], 1u);
            atomicAdd(&hist[(u32)a >> 8], 1u);
        }
    }
    __syncthreads();

    // scan 1024 bins (2 per thread) -> sstart (exclusive)
    u32 a0 = hist[2 * t], a1 = hist[2 * t + 1];
    u32 tsum = a0 + a1;
    sdata[t] = tsum;
    __syncthreads();
    for (int off = 1; off < 512; off <<= 1) {
        u32 x = (t >= off) ? sdata[t - off] : 0u;
        __syncthreads();
        sdata[t] += x;
        __syncthreads();
    }
    u32 texcl = sdata[t] - tsum;
    sstart[2 * t]     = texcl;
    sstart[2 * t + 1] = texcl + a0;
    __syncthreads();

    // rezero hist (becomes rank cursor) + load this tile's mscan column
    hist[t] = 0; hist[t + 512] = 0;
    for (int i = t; i < B; i += 512)
        delta[i] = mscan[(size_t)i * nblkE + blk] - sstart[i];
    __syncthreads();

    // pass B: build permutation (staging order sorted by bin)
    #pragma unroll
    for (int k = 0; k < RECS / 512; k++) {
        int li = k * 512 + t;
        if (li < vlim) {
            u32 bin = sMeta[li] >> 8;
            u32 r = atomicAdd(&hist[bin], 1u);
            sPerm[sstart[bin] + r] = (u16)li;
        }
    }
    __syncthreads();

    // pass C: write out in sorted order; consecutive j -> consecutive gslot
    #pragma unroll
    for (int k = 0; k < RECS / 512; k++) {
        int j = k * 512 + t;
        if (j < vlim) {
            int li = sPerm[j];
            u32 pv = sPay[li];
            u32 mt = sMeta[li];
            u32 gs = (u32)j + delta[mt >> 8];   // = mscan base + rank (u32 wrap ok)
            pay[gs]  = pv;
            loc8[gs] = (u8)(mt & 255u);
        }
    }
}

__global__ void k_bucket(const u32* __restrict__ pay,
                         const u8* __restrict__ loc8,
                         const u32* __restrict__ mscan,
                         u32* __restrict__ row_ptr,
                         u32* __restrict__ colw,
                         int N, int E, int B, int nblkE) {
    __shared__ u32 hist[BKT];
    __shared__ u32 excl[BKT];
    __shared__ u32 sdata[256];
    int b = blockIdx.x;
    int t = threadIdx.x;
    int node0 = b * BKT;
    int nnodes = N - node0; if (nnodes > BKT) nnodes = BKT;
    size_t flat0 = (size_t)b * nblkE;
    u32 seg_s = mscan[flat0];
    u32 seg_e = (b + 1 < B) ? mscan[flat0 + nblkE] : (u32)(2 * E);
    hist[t] = 0;
    __syncthreads();
    for (u32 j = seg_s + t; j < seg_e; j += 256)
        atomicAdd(&hist[loc8[j]], 1u);
    __syncthreads();
    u32 tsum = hist[t];
    sdata[t] = tsum;
    __syncthreads();
    for (int off = 1; off < 256; off <<= 1) {
        u32 x = (t >= off) ? sdata[t - off] : 0u;
        __syncthreads();
        sdata[t] += x;
        __syncthreads();
    }
    u32 texcl = sdata[t] - tsum;
    excl[t] = texcl;
    if (t < nnodes) row_ptr[node0 + t] = seg_s + texcl;
    if (b == 0 && t == 0) row_ptr[N] = (u32)(2 * E);
    __syncthreads();
    for (u32 j = seg_s + t; j < seg_e; j += 256) {
        u32 loc = loc8[j];
        u32 pos = atomicAdd(&excl[loc], 1u);
        colw[seg_s + pos] = pay[j];
    }
}

// --- conv: 2 rows per 8-lane group (wave = 16 consecutive rows) ----------

__device__ __forceinline__ void fma8(const uint4& q, float wj, float acc[8]) {
    const __half2* hp = (const __half2*)&q;
    #pragma unroll
    for (int k = 0; k < 4; k++) {
        float2 f = __half22float2(hp[k]);
        acc[2 * k]     += f.x * wj;
        acc[2 * k + 1] += f.y * wj;
    }
}

// two rows in lockstep; 4+4 interleaved branch-free load batches.
// inactive/dummy lanes carry u=0 -> cx=0 (cached row 0), cy=0 exact.
__device__ __forceinline__ void gather2(const __half* __restrict__ x,
                                        const u32* __restrict__ colw,
                                        u32 s0, u32 e0, u32 s1, u32 e1,
                                        int g, int sub,
                                        float accA[8], float accB[8]) {
    int lb = g << 3;
    u32 bA = s0, bB = s1;
    while (bA < e0 || bB < e1) {
        u32 uA = (bA + (u32)sub < e0 && bA < e0) ? colw[bA + sub] : 0u;
        u32 uB = (bB + (u32)sub < e1 && bB < e1) ? colw[bB + sub] : 0u;
        int   cxA = (int)(uA >> 14);
        float cyA = (float)(uA & 16383u) * (1.0f / 16384.0f);
        int   cxB = (int)(uB >> 14);
        float cyB = (float)(uB & 16383u) * (1.0f / 16384.0f);
        #pragma unroll
        for (int h = 0; h < 2; h++) {
            int j0 = h * 4;
            int a0 = __shfl(cxA, lb + j0 + 0, 64), a1 = __shfl(cxA, lb + j0 + 1, 64);
            int a2 = __shfl(cxA, lb + j0 + 2, 64), a3 = __shfl(cxA, lb + j0 + 3, 64);
            int b0 = __shfl(cxB, lb + j0 + 0, 64), b1 = __shfl(cxB, lb + j0 + 1, 64);
            int b2 = __shfl(cxB, lb + j0 + 2, 64), b3 = __shfl(cxB, lb + j0 + 3, 64);
            uint4 qa0 = *(const uint4*)(x + (size_t)a0 * DIM + sub * 8);
            uint4 qa1 = *(const uint4*)(x + (size_t)a1 * DIM + sub * 8);
            uint4 qa2 = *(const uint4*)(x + (size_t)a2 * DIM + sub * 8);
            uint4 qa3 = *(const uint4*)(x + (size_t)a3 * DIM + sub * 8);
            uint4 qb0 = *(const uint4*)(x + (size_t)b0 * DIM + sub * 8);
            uint4 qb1 = *(const uint4*)(x + (size_t)b1 * DIM + sub * 8);
            uint4 qb2 = *(const uint4*)(x + (size_t)b2 * DIM + sub * 8);
            uint4 qb3 = *(const uint4*)(x + (size_t)b3 * DIM + sub * 8);
            float wa0 = __shfl(cyA, lb + j0 + 0, 64), wa1 = __shfl(cyA, lb + j0 + 1, 64);
            float wa2 = __shfl(cyA, lb + j0 + 2, 64), wa3 = __shfl(cyA, lb + j0 + 3, 64);
            float wb0 = __shfl(cyB, lb + j0 + 0, 64), wb1 = __shfl(cyB, lb + j0 + 1, 64);
            float wb2 = __shfl(cyB, lb + j0 + 2, 64), wb3 = __shfl(cyB, lb + j0 + 3, 64);
            fma8(qa0, wa0, accA); fma8(qa1, wa1, accA);
            fma8(qa2, wa2, accA); fma8(qa3, wa3, accA);
            fma8(qb0, wb0, accB); fma8(qb1, wb1, accB);
            fma8(qb2, wb2, accB); fma8(qb3, wb3, accB);
        }
        bA += 8; bB += 8;
    }
}

__device__ __forceinline__ void finish1(float acc[8], float rdeno, __half2 hv[4]) {
    #pragma unroll
    for (int k = 0; k < 4; k++) {
        float v0 = acc[2 * k] * rdeno;
        float v1 = acc[2 * k + 1] * rdeno;
        v0 = (v0 >= 0.0f) ? v0 : NEG_SLOPE * v0;
        v1 = (v1 >= 0.0f) ? v1 : NEG_SLOPE * v1;
        hv[k] = __floats2half2_rn(v0, v1);
    }
}

__global__ void k_conv1(const __half* __restrict__ x0h,
                        const u32* __restrict__ row_ptr,
                        const u32* __restrict__ colw,
                        __half* __restrict__ x1h, int N) {
    int wave = (blockIdx.x * 256 + threadIdx.x) >> 6;
    int g    = (threadIdx.x >> 3) & 7;
    int sub  = threadIdx.x & 7;
    int r0   = wave * 16 + g * 2;
    int r1   = r0 + 1;
    if (r0 >= N) return;
    u32 s0 = row_ptr[r0], e0 = row_ptr[r0 + 1];
    u32 s1 = 0, e1 = 0;
    if (r1 < N) { s1 = row_ptr[r1]; e1 = row_ptr[r1 + 1]; }
    float accA[8] = {0,0,0,0,0,0,0,0};
    float accB[8] = {0,0,0,0,0,0,0,0};
    gather2(x0h, colw, s0, e0, s1, e1, g, sub, accA, accB);
    __half2 hv[4];
    finish1(accA, 1.0f / fmaxf((float)(e0 - s0), 1.0f), hv);
    *(uint4*)(x1h + (size_t)r0 * DIM + sub * 8) = *(const uint4*)hv;
    if (r1 < N) {
        finish1(accB, 1.0f / fmaxf((float)(e1 - s1), 1.0f), hv);
        *(uint4*)(x1h + (size_t)r1 * DIM + sub * 8) = *(const uint4*)hv;
    }
}

__device__ __forceinline__ void finish2(const uint4& q0, const uint4& q1,
                                        float acc[8], float rdeno, float r[8]) {
    const __half2* h0 = (const __half2*)&q0;
    const __half2* h1 = (const __half2*)&q1;
    #pragma unroll
    for (int k = 0; k < 4; k++) {
        float2 a = __half22float2(h0[k]);
        float2 b = __half22float2(h1[k]);
        float x2a = acc[2 * k] * rdeno;
        float x2b = acc[2 * k + 1] * rdeno;
        x2a = (x2a >= 0.0f) ? x2a : NEG_SLOPE * x2a;
        x2b = (x2b >= 0.0f) ? x2b : NEG_SLOPE * x2b;
        r[2 * k]     = a.x + b.x + x2a;
        r[2 * k + 1] = a.y + b.y + x2b;
    }
}

__global__ void k_conv2(const __half* __restrict__ x0h,
                        const __half* __restrict__ x1h,
                        const u32* __restrict__ row_ptr,
                        const u32* __restrict__ colw,
                        float* __restrict__ out, int N) {
    int wave = (blockIdx.x * 256 + threadIdx.x) >> 6;
    int g    = (threadIdx.x >> 3) & 7;
    int sub  = threadIdx.x & 7;
    int r0   = wave * 16 + g * 2;
    int r1   = r0 + 1;
    if (r0 >= N) return;
    u32 s0 = row_ptr[r0], e0 = row_ptr[r0 + 1];
    u32 s1 = 0, e1 = 0;
    if (r1 < N) { s1 = row_ptr[r1]; e1 = row_ptr[r1 + 1]; }
    // hoist own-row loads so they overlap the gather latency
    uint4 qa0 = *(const uint4*)(x0h + (size_t)r0 * DIM + sub * 8);
    uint4 qa1 = *(const uint4*)(x1h + (size_t)r0 * DIM + sub * 8);
    uint4 qb0, qb1;
    if (r1 < N) {
        qb0 = *(const uint4*)(x0h + (size_t)r1 * DIM + sub * 8);
        qb1 = *(const uint4*)(x1h + (size_t)r1 * DIM + sub * 8);
    }
    float accA[8] = {0,0,0,0,0,0,0,0};
    float accB[8] = {0,0,0,0,0,0,0,0};
    gather2(x1h, colw, s0, e0, s1, e1, g, sub, accA, accB);
    float r[8];
    finish2(qa0, qa1, accA, 1.0f / fmaxf((float)(e0 - s0), 1.0f), r);
    float* op = out + (size_t)r0 * DIM + sub * 8;
    *(float4*)(op)     = make_float4(r[0], r[1], r[2], r[3]);
    *(float4*)(op + 4) = make_float4(r[4], r[5], r[6], r[7]);
    if (r1 < N) {
        finish2(qb0, qb1, accB, 1.0f / fmaxf((float)(e1 - s1), 1.0f), r);
        op = out + (size_t)r1 * DIM + sub * 8;
        *(float4*)(op)     = make_float4(r[0], r[1], r[2], r[3]);
        *(float4*)(op + 4) = make_float4(r[4], r[5], r[6], r[7]);
    }
}

static inline size_t align16(size_t x) { return (x + 15) & ~(size_t)15; }

extern "C" void kernel_launch(void* const* d_in, const int* in_sizes, int n_in,
                              void* d_out, int out_size, void* d_ws, size_t ws_size,
                              hipStream_t stream) {
    const int N = in_sizes[0] / DIM;      // 200000
    const int E = in_sizes[1] / 2;        // 600000

    const float* emb = (const float*)d_in[0];
    const int*   ei  = (const int*)d_in[1];
    const float* w   = (const float*)d_in[2];
    float*       out = (float*)d_out;

    const int B     = (N + BKT - 1) / BKT;          // 782 buckets
    const int nblkE = (E + TILEP - 1) / TILEP;      // 147 pair tiles
    const int M     = B * nblkE;                    // 114,954
    const int nb1   = (M + STILE - 1) / STILE;      // 57 (<=256)
    const int rb    = (N + 31) / 32;                // 6250 norm blocks (512 thr)
    const int cvb   = (N + 63) / 64;                // conv: 64 rows/block (2/group)

    char* ws = (char*)d_ws;
    size_t off = 0;
    __half* x0h    = (__half*)(ws + off); off += align16((size_t)N * DIM * 2);
    __half* x1h    = (__half*)(ws + off); off += align16((size_t)N * DIM * 2);
    u32*    pay    = (u32*)(ws + off);    off += align16((size_t)2 * E * 4);
    u8*     loc8   = (u8*)(ws + off);     off += align16((size_t)2 * E);
    u32*    colw   = (u32*)(ws + off);    off += align16((size_t)2 * E * 4);
    u32*    mat    = (u32*)(ws + off);    off += align16((size_t)M * 4);
    u32*    mscan  = (u32*)(ws + off);    off += align16((size_t)M * 4);
    u32*    row_ptr= (u32*)(ws + off);    off += align16((size_t)(N + 1) * 4);
    u32*    bsum   = (u32*)(ws + off);    off += align16(256 * 4);

    k_norm_hist<<<rb + nblkE, 512, 0, stream>>>(emb, x0h, ei, mat, N, E, rb, B, nblkE);
    k_scan1  <<<nb1, 256, 0, stream>>>(mat, mscan, bsum, M);
    k_scanfix<<<(M + 255) / 256, 256, 0, stream>>>(mscan, bsum, nb1, M);
    k_place  <<<nblkE, 512, 0, stream>>>(ei, w, mscan, pay, loc8, E, nblkE, B);
    k_bucket <<<B, 256, 0, stream>>>(pay, loc8, mscan, row_ptr, colw, N, E, B, nblkE);

    k_conv1<<<cvb, 256, 0, stream>>>(x0h, row_ptr, colw, x1h, N);
    k_conv2<<<cvb, 256, 0, stream>>>(x0h, x1h, row_ptr, colw, out, N);
}

// Round 8
// 213.137 us; speedup vs baseline: 1.0643x; 1.0348x over previous
//
#include <hip/hip_runtime.h>
#include <hip/hip_fp16.h>

#define DIM 64
#define NEG_SLOPE 0.01f
#define BKT 256          // nodes per bucket (LDS hist granularity in k_bucket)
#define TILEP 4096       // symmetric PAIRS per hist/place tile (= 8192 records)
#define RECS (TILEP * 2) // records per tile
#define STILE 2048       // scan1 tile: 256 thr x 8

typedef unsigned u32;
typedef unsigned short u16;
typedef unsigned char u8;

// ---------------------------------------------------------------------------
// Round 16: isolate the proven-good pieces. R15's 2-row pairing spilled
// (VGPR capped at 64, scratch traffic = +34MB WRITE +14MB FETCH). R13's
// guarded batch-4 never actually batched (VGPR=20: guards -> re-serialized).
// R14's branch-free batch-8 DID batch (VGPR=48, WRITE exactly 50MB) but was
// poisoned by the degree-sort's scattered rows. This round: R13 row mapping
// (1 row per 8-lane group, wave = 8 consecutive rows) + R14 branch-free
// batch-8 gather, NO sort. Build pipeline unchanged from R12.
// ---------------------------------------------------------------------------

__global__ void k_norm_hist(const float* __restrict__ emb,
                            __half* __restrict__ x0h,
                            const int* __restrict__ p,
                            u32* __restrict__ mat,
                            int N, int E, int rb, int B, int nblkE) {
    int t = threadIdx.x;
    if ((int)blockIdx.x < rb) {
        // L2-normalize: 16 lanes/row, 4 rows/wave, 8 waves -> 32 rows/block
        int lane = t & 63;
        int row  = blockIdx.x * 32 + (t >> 6) * 4 + (lane >> 4);
        int l16  = lane & 15;
        if (row >= N) return;
        float4 v = *(const float4*)(emb + (size_t)row * DIM + l16 * 4);
        float s = v.x * v.x + v.y * v.y + v.z * v.z + v.w * v.w;
        #pragma unroll
        for (int m = 1; m < 16; m <<= 1) s += __shfl_xor(s, m, 64);
        float inv = 1.0f / fmaxf(sqrtf(s), 1e-12f);
        union { uint2 u; __half2 h[2]; } pk;
        pk.h[0] = __floats2half2_rn(v.x * inv, v.y * inv);
        pk.h[1] = __floats2half2_rn(v.z * inv, v.w * inv);
        *(uint2*)(x0h + (size_t)row * DIM + l16 * 4) = pk.u;
    } else {
        __shared__ u32 hist[800];           // B = 782 bins
        int blk = blockIdx.x - rb;
        for (int i = t; i < B; i += 512) hist[i] = 0;
        __syncthreads();
        int base = blk * TILEP;
        #pragma unroll
        for (int k = 0; k < TILEP / 512; k++) {
            int pe = base + k * 512 + t;
            if (pe < E) {
                int a = p[pe];
                int b = p[pe + E];
                atomicAdd(&hist[(u32)b >> 8], 1u);
                atomicAdd(&hist[(u32)a >> 8], 1u);
            }
        }
        __syncthreads();
        for (int i = t; i < B; i += 512) mat[(size_t)i * nblkE + blk] = hist[i];
    }
}

__global__ void k_scan1(const u32* __restrict__ in, u32* __restrict__ out,
                        u32* __restrict__ bsum, int M) {
    __shared__ u32 sdata[256];
    int t = threadIdx.x;
    int base = blockIdx.x * STILE + t * 8;
    u32 v[8]; u32 tsum = 0;
    #pragma unroll
    for (int k = 0; k < 8; k++) {
        int i = base + k;
        v[k] = (i < M) ? in[i] : 0u;
        tsum += v[k];
    }
    sdata[t] = tsum;
    __syncthreads();
    for (int off = 1; off < 256; off <<= 1) {
        u32 x = (t >= off) ? sdata[t - off] : 0u;
        __syncthreads();
        sdata[t] += x;
        __syncthreads();
    }
    u32 run = sdata[t] - tsum;
    if (t == 255) bsum[blockIdx.x] = sdata[255];
    #pragma unroll
    for (int k = 0; k < 8; k++) {
        int i = base + k;
        if (i < M) out[i] = run;
        run += v[k];
    }
}

// fold block offsets into mscan; each block re-scans bsum (nb<=256) in LDS
__global__ void k_scanfix(u32* __restrict__ mscan,
                          const u32* __restrict__ bsum, int nb, int M) {
    __shared__ u32 sdata[256];
    __shared__ u32 sexcl[256];
    int t = threadIdx.x;
    u32 v = (t < nb) ? bsum[t] : 0u;
    sdata[t] = v;
    __syncthreads();
    for (int off = 1; off < 256; off <<= 1) {
        u32 x = (t >= off) ? sdata[t - off] : 0u;
        __syncthreads();
        sdata[t] += x;
        __syncthreads();
    }
    sexcl[t] = sdata[t] - v;
    __syncthreads();
    int i = blockIdx.x * 256 + t;
    if (i < M) mscan[i] += sexcl[i >> 11];
}

// LDS tile sort + coalesced run write-out. ~94KB LDS, 1 block/CU.
__global__ __launch_bounds__(512, 1)
void k_place(const int* __restrict__ p, const float* __restrict__ w,
             const u32* __restrict__ mscan,
             u32* __restrict__ pay, u8* __restrict__ loc8,
             int E, int nblkE, int B) {
    __shared__ u32 sPay[RECS];    // 32KB
    __shared__ u32 sMeta[RECS];   // 32KB (= dst node id; bin=>>8, loc=&255)
    __shared__ u16 sPerm[RECS];   // 16KB
    __shared__ u32 hist[1024];    // counts -> (rezeroed) cursors
    __shared__ u32 sstart[1024];
    __shared__ u32 delta[1024];
    __shared__ u32 sdata[512];

    int blk = blockIdx.x;
    int t = threadIdx.x;
    int base = blk * TILEP;
    int rem = E - base;                       // pairs in this tile
    int vlim = rem * 2; if (vlim > RECS) vlim = RECS;

    hist[t] = 0; hist[t + 512] = 0;
    __syncthreads();

    // pass A: stage records + count bins
    #pragma unroll
    for (int k = 0; k < TILEP / 512; k++) {
        int pe = base + k * 512 + t;
        if (pe < E) {
            int a = p[pe];
            int b = p[pe + E];
            float wf = w[pe];
            float wb = w[pe + E];
            u32 wf14 = (u32)(wf * 16384.0f + 0.5f); if (wf14 > 16383u) wf14 = 16383u;
            u32 wb14 = (u32)(wb * 16384.0f + 0.5f); if (wb14 > 16383u) wb14 = 16383u;
            int li = (k * 512 + t) * 2;
            sPay[li]      = ((u32)a << 14) | wf14;   // fwd record: dst = b
            sMeta[li]     = (u32)b;
            sPay[li + 1]  = ((u32)b << 14) | wb14;   // bwd record: dst = a
            sMeta[li + 1] = (u32)a;
            atomicAdd(&hist[(u32)b >> 8], 1u);
            atomicAdd(&hist[(u32)a >> 8], 1u);
        }
    }
    __syncthreads();

    // scan 1024 bins (2 per thread) -> sstart (exclusive)
    u32 a0 = hist[2 * t], a1 = hist[2 * t + 1];
    u32 tsum = a0 + a1;
    sdata[t] = tsum;
    __syncthreads();
    for (int off = 1; off < 512; off <<= 1) {
        u32 x = (t >= off) ? sdata[t - off] : 0u;
        __syncthreads();
        sdata[t] += x;
        __syncthreads();
    }
    u32 texcl = sdata[t] - tsum;
    sstart[2 * t]     = texcl;
    sstart[2 * t + 1] = texcl + a0;
    __syncthreads();

    // rezero hist (becomes rank cursor) + load this tile's mscan column
    hist[t] = 0; hist[t + 512] = 0;
    for (int i = t; i < B; i += 512)
        delta[i] = mscan[(size_t)i * nblkE + blk] - sstart[i];
    __syncthreads();

    // pass B: build permutation (staging order sorted by bin)
    #pragma unroll
    for (int k = 0; k < RECS / 512; k++) {
        int li = k * 512 + t;
        if (li < vlim) {
            u32 bin = sMeta[li] >> 8;
            u32 r = atomicAdd(&hist[bin], 1u);
            sPerm[sstart[bin] + r] = (u16)li;
        }
    }
    __syncthreads();

    // pass C: write out in sorted order; consecutive j -> consecutive gslot
    #pragma unroll
    for (int k = 0; k < RECS / 512; k++) {
        int j = k * 512 + t;
        if (j < vlim) {
            int li = sPerm[j];
            u32 pv = sPay[li];
            u32 mt = sMeta[li];
            u32 gs = (u32)j + delta[mt >> 8];   // = mscan base + rank (u32 wrap ok)
            pay[gs]  = pv;
            loc8[gs] = (u8)(mt & 255u);
        }
    }
}

__global__ void k_bucket(const u32* __restrict__ pay,
                         const u8* __restrict__ loc8,
                         const u32* __restrict__ mscan,
                         u32* __restrict__ row_ptr,
                         u32* __restrict__ colw,
                         int N, int E, int B, int nblkE) {
    __shared__ u32 hist[BKT];
    __shared__ u32 excl[BKT];
    __shared__ u32 sdata[256];
    int b = blockIdx.x;
    int t = threadIdx.x;
    int node0 = b * BKT;
    int nnodes = N - node0; if (nnodes > BKT) nnodes = BKT;
    size_t flat0 = (size_t)b * nblkE;
    u32 seg_s = mscan[flat0];
    u32 seg_e = (b + 1 < B) ? mscan[flat0 + nblkE] : (u32)(2 * E);
    hist[t] = 0;
    __syncthreads();
    for (u32 j = seg_s + t; j < seg_e; j += 256)
        atomicAdd(&hist[loc8[j]], 1u);
    __syncthreads();
    u32 tsum = hist[t];
    sdata[t] = tsum;
    __syncthreads();
    for (int off = 1; off < 256; off <<= 1) {
        u32 x = (t >= off) ? sdata[t - off] : 0u;
        __syncthreads();
        sdata[t] += x;
        __syncthreads();
    }
    u32 texcl = sdata[t] - tsum;
    excl[t] = texcl;
    if (t < nnodes) row_ptr[node0 + t] = seg_s + texcl;
    if (b == 0 && t == 0) row_ptr[N] = (u32)(2 * E);
    __syncthreads();
    for (u32 j = seg_s + t; j < seg_e; j += 256) {
        u32 loc = loc8[j];
        u32 pos = atomicAdd(&excl[loc], 1u);
        colw[seg_s + pos] = pay[j];
    }
}

// --- conv: 8 rows/wave, 8 lanes/row, lane covers dims [sub*8, sub*8+8) ----

__device__ __forceinline__ void fma8(const uint4& q, float wj, float acc[8]) {
    const __half2* hp = (const __half2*)&q;
    #pragma unroll
    for (int k = 0; k < 4; k++) {
        float2 f = __half22float2(hp[k]);
        acc[2 * k]     += f.x * wj;
        acc[2 * k + 1] += f.y * wj;
    }
}

// branch-free batch-8: lanes with sub>=m carry u=0 -> cx=0 (cached row 0),
// cy=0 (exact zero weight); all 8 loads issue back-to-back (VGPR ~48, no
// spill — verified in R14), then all 8 FMAs consume.
__device__ __forceinline__ void gather8(const __half* __restrict__ x,
                                        const u32* __restrict__ colw,
                                        u32 s, u32 e, int g, int sub,
                                        float acc[8]) {
    int lb = g << 3;
    for (u32 base = s; base < e; base += 8) {
        int m = (int)(e - base); if (m > 8) m = 8;
        u32 u = (sub < m) ? colw[base + sub] : 0u;
        int   cx = (int)(u >> 14);
        float cy = (float)(u & 16383u) * (1.0f / 16384.0f);
        int s0 = __shfl(cx, lb + 0, 64), s1 = __shfl(cx, lb + 1, 64);
        int s2 = __shfl(cx, lb + 2, 64), s3 = __shfl(cx, lb + 3, 64);
        int s4 = __shfl(cx, lb + 4, 64), s5 = __shfl(cx, lb + 5, 64);
        int s6 = __shfl(cx, lb + 6, 64), s7 = __shfl(cx, lb + 7, 64);
        uint4 q0 = *(const uint4*)(x + (size_t)s0 * DIM + sub * 8);
        uint4 q1 = *(const uint4*)(x + (size_t)s1 * DIM + sub * 8);
        uint4 q2 = *(const uint4*)(x + (size_t)s2 * DIM + sub * 8);
        uint4 q3 = *(const uint4*)(x + (size_t)s3 * DIM + sub * 8);
        uint4 q4 = *(const uint4*)(x + (size_t)s4 * DIM + sub * 8);
        uint4 q5 = *(const uint4*)(x + (size_t)s5 * DIM + sub * 8);
        uint4 q6 = *(const uint4*)(x + (size_t)s6 * DIM + sub * 8);
        uint4 q7 = *(const uint4*)(x + (size_t)s7 * DIM + sub * 8);
        float w0 = __shfl(cy, lb + 0, 64), w1 = __shfl(cy, lb + 1, 64);
        float w2 = __shfl(cy, lb + 2, 64), w3 = __shfl(cy, lb + 3, 64);
        float w4 = __shfl(cy, lb + 4, 64), w5 = __shfl(cy, lb + 5, 64);
        float w6 = __shfl(cy, lb + 6, 64), w7 = __shfl(cy, lb + 7, 64);
        fma8(q0, w0, acc); fma8(q1, w1, acc);
        fma8(q2, w2, acc); fma8(q3, w3, acc);
        fma8(q4, w4, acc); fma8(q5, w5, acc);
        fma8(q6, w6, acc); fma8(q7, w7, acc);
    }
}

__global__ void k_conv1(const __half* __restrict__ x0h,
                        const u32* __restrict__ row_ptr,
                        const u32* __restrict__ colw,
                        __half* __restrict__ x1h, int N) {
    int wave = (blockIdx.x * 256 + threadIdx.x) >> 6;
    int g    = (threadIdx.x >> 3) & 7;
    int sub  = threadIdx.x & 7;
    int row  = wave * 8 + g;
    if (row >= N) return;
    u32 s = row_ptr[row], e = row_ptr[row + 1];
    float acc[8] = {0, 0, 0, 0, 0, 0, 0, 0};
    gather8(x0h, colw, s, e, g, sub, acc);
    float rdeno = 1.0f / fmaxf((float)(e - s), 1.0f);
    __half2 hv[4];
    #pragma unroll
    for (int k = 0; k < 4; k++) {
        float v0 = acc[2 * k] * rdeno;
        float v1 = acc[2 * k + 1] * rdeno;
        v0 = (v0 >= 0.0f) ? v0 : NEG_SLOPE * v0;
        v1 = (v1 >= 0.0f) ? v1 : NEG_SLOPE * v1;
        hv[k] = __floats2half2_rn(v0, v1);
    }
    *(uint4*)(x1h + (size_t)row * DIM + sub * 8) = *(const uint4*)hv;
}

__global__ void k_conv2(const __half* __restrict__ x0h,
                        const __half* __restrict__ x1h,
                        const u32* __restrict__ row_ptr,
                        const u32* __restrict__ colw,
                        float* __restrict__ out, int N) {
    int wave = (blockIdx.x * 256 + threadIdx.x) >> 6;
    int g    = (threadIdx.x >> 3) & 7;
    int sub  = threadIdx.x & 7;
    int row  = wave * 8 + g;
    if (row >= N) return;
    u32 s = row_ptr[row], e = row_ptr[row + 1];
    // hoist own-row loads so they overlap the gather latency
    uint4 q0 = *(const uint4*)(x0h + (size_t)row * DIM + sub * 8);
    uint4 q1 = *(const uint4*)(x1h + (size_t)row * DIM + sub * 8);
    float acc[8] = {0, 0, 0, 0, 0, 0, 0, 0};
    gather8(x1h, colw, s, e, g, sub, acc);
    float rdeno = 1.0f / fmaxf((float)(e - s), 1.0f);
    const __half2* h0 = (const __half2*)&q0;
    const __half2* h1 = (const __half2*)&q1;
    float r[8];
    #pragma unroll
    for (int k = 0; k < 4; k++) {
        float2 a = __half22float2(h0[k]);
        float2 b = __half22float2(h1[k]);
        float x2a = acc[2 * k] * rdeno;
        float x2b = acc[2 * k + 1] * rdeno;
        x2a = (x2a >= 0.0f) ? x2a : NEG_SLOPE * x2a;
        x2b = (x2b >= 0.0f) ? x2b : NEG_SLOPE * x2b;
        r[2 * k]     = a.x + b.x + x2a;
        r[2 * k + 1] = a.y + b.y + x2b;
    }
    float* op = out + (size_t)row * DIM + sub * 8;
    *(float4*)(op)     = make_float4(r[0], r[1], r[2], r[3]);
    *(float4*)(op + 4) = make_float4(r[4], r[5], r[6], r[7]);
}

static inline size_t align16(size_t x) { return (x + 15) & ~(size_t)15; }

extern "C" void kernel_launch(void* const* d_in, const int* in_sizes, int n_in,
                              void* d_out, int out_size, void* d_ws, size_t ws_size,
                              hipStream_t stream) {
    const int N = in_sizes[0] / DIM;      // 200000
    const int E = in_sizes[1] / 2;        // 600000

    const float* emb = (const float*)d_in[0];
    const int*   ei  = (const int*)d_in[1];
    const float* w   = (const float*)d_in[2];
    float*       out = (float*)d_out;

    const int B     = (N + BKT - 1) / BKT;          // 782 buckets
    const int nblkE = (E + TILEP - 1) / TILEP;      // 147 pair tiles
    const int M     = B * nblkE;                    // 114,954
    const int nb1   = (M + STILE - 1) / STILE;      // 57 (<=256)
    const int rb    = (N + 31) / 32;                // 6250 norm blocks (512 thr)
    const int cvb   = (N + 31) / 32;                // conv blocks: 32 rows/block

    char* ws = (char*)d_ws;
    size_t off = 0;
    __half* x0h    = (__half*)(ws + off); off += align16((size_t)N * DIM * 2);
    __half* x1h    = (__half*)(ws + off); off += align16((size_t)N * DIM * 2);
    u32*    pay    = (u32*)(ws + off);    off += align16((size_t)2 * E * 4);
    u8*     loc8   = (u8*)(ws + off);     off += align16((size_t)2 * E);
    u32*    colw   = (u32*)(ws + off);    off += align16((size_t)2 * E * 4);
    u32*    mat    = (u32*)(ws + off);    off += align16((size_t)M * 4);
    u32*    mscan  = (u32*)(ws + off);    off += align16((size_t)M * 4);
    u32*    row_ptr= (u32*)(ws + off);    off += align16((size_t)(N + 1) * 4);
    u32*    bsum   = (u32*)(ws + off);    off += align16(256 * 4);

    k_norm_hist<<<rb + nblkE, 512, 0, stream>>>(emb, x0h, ei, mat, N, E, rb, B, nblkE);
    k_scan1  <<<nb1, 256, 0, stream>>>(mat, mscan, bsum, M);
    k_scanfix<<<(M + 255) / 256, 256, 0, stream>>>(mscan, bsum, nb1, M);
    k_place  <<<nblkE, 512, 0, stream>>>(ei, w, mscan, pay, loc8, E, nblkE, B);
    k_bucket <<<B, 256, 0, stream>>>(pay, loc8, mscan, row_ptr, colw, N, E, B, nblkE);

    k_conv1<<<cvb, 256, 0, stream>>>(x0h, row_ptr, colw, x1h, N);
    k_conv2<<<cvb, 256, 0, stream>>>(x0h, x1h, row_ptr, colw, out, N);
}

// Round 9
// 209.139 us; speedup vs baseline: 1.0847x; 1.0191x over previous
//
#include <hip/hip_runtime.h>
#include <hip/hip_fp16.h>

#define DIM 64
#define NEG_SLOPE 0.01f
#define BKT 256          // nodes per bucket (LDS hist granularity in k_bucket)
#define TILEP 2048       // symmetric PAIRS per hist/place tile (= 4096 records)
#define RECS (TILEP * 2) // records per tile
#define STILE 2048       // scan1 tile: 256 thr x 8

typedef unsigned u32;
typedef unsigned short u16;
typedef unsigned char u8;

// ---------------------------------------------------------------------------
// Round 17: convs are at their random-access fabric floor (R13/15/16:
// 35/163/102 in-flight loads per CU all land 41-52us at 3.3-3.9TB/s) ->
// revert to the proven VGPR-20 simple gather (R12/R13, 41.5us) and attack
// the build phase instead:
//  - TILEP 4096->2048: k_place 147 blocks@1/CU (57% CUs idle) -> 293
//    blocks@2/CU (54KB LDS), work/block halved
//  - k_scanfix DELETED: place/bucket scan the <=112-entry bsum inline
//  - k_bucket stages its ~1535 records in LDS once (was 2 global reads)
// 6 launches (was 8).
// ---------------------------------------------------------------------------

__global__ void k_norm_hist(const float* __restrict__ emb,
                            __half* __restrict__ x0h,
                            const int* __restrict__ p,
                            u32* __restrict__ mat,
                            int N, int E, int rb, int B, int nblkE) {
    int t = threadIdx.x;
    if ((int)blockIdx.x < rb) {
        // L2-normalize: 16 lanes/row, 4 rows/wave, 8 waves -> 32 rows/block
        int lane = t & 63;
        int row  = blockIdx.x * 32 + (t >> 6) * 4 + (lane >> 4);
        int l16  = lane & 15;
        if (row >= N) return;
        float4 v = *(const float4*)(emb + (size_t)row * DIM + l16 * 4);
        float s = v.x * v.x + v.y * v.y + v.z * v.z + v.w * v.w;
        #pragma unroll
        for (int m = 1; m < 16; m <<= 1) s += __shfl_xor(s, m, 64);
        float inv = 1.0f / fmaxf(sqrtf(s), 1e-12f);
        union { uint2 u; __half2 h[2]; } pk;
        pk.h[0] = __floats2half2_rn(v.x * inv, v.y * inv);
        pk.h[1] = __floats2half2_rn(v.z * inv, v.w * inv);
        *(uint2*)(x0h + (size_t)row * DIM + l16 * 4) = pk.u;
    } else {
        __shared__ u32 hist[800];           // B = 782 bins
        int blk = blockIdx.x - rb;
        for (int i = t; i < B; i += 512) hist[i] = 0;
        __syncthreads();
        int base = blk * TILEP;
        #pragma unroll
        for (int k = 0; k < TILEP / 512; k++) {
            int pe = base + k * 512 + t;
            if (pe < E) {
                int a = p[pe];
                int b = p[pe + E];
                atomicAdd(&hist[(u32)b >> 8], 1u);
                atomicAdd(&hist[(u32)a >> 8], 1u);
            }
        }
        __syncthreads();
        for (int i = t; i < B; i += 512) mat[(size_t)i * nblkE + blk] = hist[i];
    }
}

__global__ void k_scan1(const u32* __restrict__ in, u32* __restrict__ out,
                        u32* __restrict__ bsum, int M) {
    __shared__ u32 sdata[256];
    int t = threadIdx.x;
    int base = blockIdx.x * STILE + t * 8;
    u32 v[8]; u32 tsum = 0;
    #pragma unroll
    for (int k = 0; k < 8; k++) {
        int i = base + k;
        v[k] = (i < M) ? in[i] : 0u;
        tsum += v[k];
    }
    sdata[t] = tsum;
    __syncthreads();
    for (int off = 1; off < 256; off <<= 1) {
        u32 x = (t >= off) ? sdata[t - off] : 0u;
        __syncthreads();
        sdata[t] += x;
        __syncthreads();
    }
    u32 run = sdata[t] - tsum;
    if (t == 255) bsum[blockIdx.x] = sdata[255];
    #pragma unroll
    for (int k = 0; k < 8; k++) {
        int i = base + k;
        if (i < M) out[i] = run;
        run += v[k];
    }
}

// LDS tile sort + coalesced run write-out. ~54KB LDS -> 2 blocks/CU.
__global__ __launch_bounds__(512, 4)
void k_place(const int* __restrict__ p, const float* __restrict__ w,
             const u32* __restrict__ mscan, const u32* __restrict__ bsum,
             u32* __restrict__ pay, u8* __restrict__ loc8,
             int E, int nblkE, int B, int nb1) {
    __shared__ u32 sPay[RECS];    // 16KB
    __shared__ u32 sMeta[RECS];   // 16KB (= dst node id; bin=>>8, loc=&255)
    __shared__ u16 sPerm[RECS];   // 8KB
    __shared__ u32 hist[1024];    // counts -> (rezeroed) cursors
    __shared__ u32 sstart[1024];
    __shared__ u32 delta[800];
    __shared__ u32 sdata[512];
    __shared__ u32 sbsE[128];     // exclusive scan of bsum (nb1 <= 128)

    int blk = blockIdx.x;
    int t = threadIdx.x;
    int base = blk * TILEP;
    int rem = E - base;                       // pairs in this tile
    int vlim = rem * 2; if (vlim > RECS) vlim = RECS;

    // inline exclusive scan of bsum (global scan-fix offsets)
    u32 bv = (t < nb1) ? bsum[t] : 0u;
    sdata[t] = bv;
    __syncthreads();
    for (int off = 1; off < 512; off <<= 1) {
        u32 x = (t >= off) ? sdata[t - off] : 0u;
        __syncthreads();
        sdata[t] += x;
        __syncthreads();
    }
    if (t < 128) sbsE[t] = sdata[t] - bv;
    hist[t] = 0; hist[t + 512] = 0;
    __syncthreads();

    // pass A: stage records + count bins
    #pragma unroll
    for (int k = 0; k < TILEP / 512; k++) {
        int pe = base + k * 512 + t;
        if (pe < E) {
            int a = p[pe];
            int b = p[pe + E];
            float wf = w[pe];
            float wb = w[pe + E];
            u32 wf14 = (u32)(wf * 16384.0f + 0.5f); if (wf14 > 16383u) wf14 = 16383u;
            u32 wb14 = (u32)(wb * 16384.0f + 0.5f); if (wb14 > 16383u) wb14 = 16383u;
            int li = (k * 512 + t) * 2;
            sPay[li]      = ((u32)a << 14) | wf14;   // fwd record: dst = b
            sMeta[li]     = (u32)b;
            sPay[li + 1]  = ((u32)b << 14) | wb14;   // bwd record: dst = a
            sMeta[li + 1] = (u32)a;
            atomicAdd(&hist[(u32)b >> 8], 1u);
            atomicAdd(&hist[(u32)a >> 8], 1u);
        }
    }
    __syncthreads();

    // scan 1024 bins (2 per thread) -> sstart (exclusive)
    u32 a0 = hist[2 * t], a1 = hist[2 * t + 1];
    u32 tsum = a0 + a1;
    sdata[t] = tsum;
    __syncthreads();
    for (int off = 1; off < 512; off <<= 1) {
        u32 x = (t >= off) ? sdata[t - off] : 0u;
        __syncthreads();
        sdata[t] += x;
        __syncthreads();
    }
    u32 texcl = sdata[t] - tsum;
    sstart[2 * t]     = texcl;
    sstart[2 * t + 1] = texcl + a0;
    __syncthreads();

    // rezero hist (becomes rank cursor) + load this tile's mscan column
    hist[t] = 0; hist[t + 512] = 0;
    for (int i = t; i < B; i += 512) {
        size_t fi = (size_t)i * nblkE + blk;
        delta[i] = mscan[fi] + sbsE[fi >> 11] - sstart[i];
    }
    __syncthreads();

    // pass B: build permutation (staging order sorted by bin)
    #pragma unroll
    for (int k = 0; k < RECS / 512; k++) {
        int li = k * 512 + t;
        if (li < vlim) {
            u32 bin = sMeta[li] >> 8;
            u32 r = atomicAdd(&hist[bin], 1u);
            sPerm[sstart[bin] + r] = (u16)li;
        }
    }
    __syncthreads();

    // pass C: write out in sorted order; consecutive j -> consecutive gslot
    #pragma unroll
    for (int k = 0; k < RECS / 512; k++) {
        int j = k * 512 + t;
        if (j < vlim) {
            int li = sPerm[j];
            u32 pv = sPay[li];
            u32 mt = sMeta[li];
            u32 gs = (u32)j + delta[mt >> 8];   // = mscan base + rank (u32 wrap ok)
            pay[gs]  = pv;
            loc8[gs] = (u8)(mt & 255u);
        }
    }
}

__global__ void k_bucket(const u32* __restrict__ pay,
                         const u8* __restrict__ loc8,
                         const u32* __restrict__ mscan,
                         const u32* __restrict__ bsum,
                         u32* __restrict__ row_ptr,
                         u32* __restrict__ colw,
                         int N, int E, int B, int nblkE, int nb1) {
    __shared__ u32 hist[BKT];
    __shared__ u32 excl[BKT];
    __shared__ u32 sdata[256];
    __shared__ u32 sexc[256];
    __shared__ u32 spay[2048];   // 8KB: staged records (span ~1535)
    __shared__ u8  sloc[2048];   // 2KB
    int b = blockIdx.x;
    int t = threadIdx.x;
    int node0 = b * BKT;
    int nnodes = N - node0; if (nnodes > BKT) nnodes = BKT;

    // inline exclusive scan of bsum
    u32 bv = (t < nb1) ? bsum[t] : 0u;
    sdata[t] = bv;
    __syncthreads();
    for (int off = 1; off < 256; off <<= 1) {
        u32 x = (t >= off) ? sdata[t - off] : 0u;
        __syncthreads();
        sdata[t] += x;
        __syncthreads();
    }
    sexc[t] = sdata[t] - bv;
    __syncthreads();

    size_t flat0 = (size_t)b * nblkE;
    u32 seg_s = mscan[flat0] + sexc[flat0 >> 11];
    u32 seg_e = (b + 1 < B) ? (mscan[flat0 + nblkE] + sexc[(flat0 + nblkE) >> 11])
                            : (u32)(2 * E);
    u32 span = seg_e - seg_s;
    u32 nst  = span < 2048u ? span : 2048u;

    hist[t] = 0;
    __syncthreads();
    // stage records once
    for (u32 j = t; j < nst; j += 256) {
        spay[j] = pay[seg_s + j];
        sloc[j] = loc8[seg_s + j];
    }
    __syncthreads();
    for (u32 j = t; j < span; j += 256) {
        u32 loc = (j < nst) ? (u32)sloc[j] : (u32)loc8[seg_s + j];
        atomicAdd(&hist[loc], 1u);
    }
    __syncthreads();
    u32 tsum = hist[t];
    sdata[t] = tsum;
    __syncthreads();
    for (int off = 1; off < 256; off <<= 1) {
        u32 x = (t >= off) ? sdata[t - off] : 0u;
        __syncthreads();
        sdata[t] += x;
        __syncthreads();
    }
    u32 texcl = sdata[t] - tsum;
    excl[t] = texcl;
    if (t < nnodes) row_ptr[node0 + t] = seg_s + texcl;
    if (b == 0 && t == 0) row_ptr[N] = (u32)(2 * E);
    __syncthreads();
    for (u32 j = t; j < span; j += 256) {
        u32 loc, pv;
        if (j < nst) { loc = sloc[j]; pv = spay[j]; }
        else         { loc = loc8[seg_s + j]; pv = pay[seg_s + j]; }
        u32 pos = atomicAdd(&excl[loc], 1u);
        colw[seg_s + pos] = pv;
    }
}

// --- conv: 8 rows/wave, 8 lanes/row, lane covers dims [sub*8, sub*8+8) ----
// Simple m-loop gather (R12/R13 proven: VGPR ~20, 55% occ, conv2 41.5us).

__device__ __forceinline__ void gather8(const __half* __restrict__ x,
                                        const u32* __restrict__ colw,
                                        u32 s, u32 e, int g, int sub,
                                        float acc[8]) {
    for (u32 base = s; base < e; base += 8) {
        int m = (int)(e - base); if (m > 8) m = 8;   // valid edges this chunk
        u32 u = 0;
        if (sub < m) u = colw[base + sub];
        int   cx = (int)(u >> 14);
        float cy = (float)(u & 16383u) * (1.0f / 16384.0f);
        for (int j = 0; j < m; j++) {               // m uniform per 8-lane group
            int   sj = __shfl(cx, (g << 3) | j, 64);
            float wj = __shfl(cy, (g << 3) | j, 64);
            uint4 q = *(const uint4*)(x + (size_t)sj * DIM + sub * 8);
            const __half2* hp = (const __half2*)&q;
            #pragma unroll
            for (int k = 0; k < 4; k++) {
                float2 f = __half22float2(hp[k]);
                acc[2 * k]     += f.x * wj;
                acc[2 * k + 1] += f.y * wj;
            }
        }
    }
}

__global__ void k_conv1(const __half* __restrict__ x0h,
                        const u32* __restrict__ row_ptr,
                        const u32* __restrict__ colw,
                        __half* __restrict__ x1h, int N) {
    int wave = (blockIdx.x * 256 + threadIdx.x) >> 6;
    int g    = (threadIdx.x >> 3) & 7;
    int sub  = threadIdx.x & 7;
    int row  = wave * 8 + g;
    if (row >= N) return;
    u32 s = row_ptr[row], e = row_ptr[row + 1];
    float acc[8] = {0, 0, 0, 0, 0, 0, 0, 0};
    gather8(x0h, colw, s, e, g, sub, acc);
    float rdeno = 1.0f / fmaxf((float)(e - s), 1.0f);
    __half2 hv[4];
    #pragma unroll
    for (int k = 0; k < 4; k++) {
        float v0 = acc[2 * k] * rdeno;
        float v1 = acc[2 * k + 1] * rdeno;
        v0 = (v0 >= 0.0f) ? v0 : NEG_SLOPE * v0;
        v1 = (v1 >= 0.0f) ? v1 : NEG_SLOPE * v1;
        hv[k] = __floats2half2_rn(v0, v1);
    }
    *(uint4*)(x1h + (size_t)row * DIM + sub * 8) = *(const uint4*)hv;
}

__global__ void k_conv2(const __half* __restrict__ x0h,
                        const __half* __restrict__ x1h,
                        const u32* __restrict__ row_ptr,
                        const u32* __restrict__ colw,
                        float* __restrict__ out, int N) {
    int wave = (blockIdx.x * 256 + threadIdx.x) >> 6;
    int g    = (threadIdx.x >> 3) & 7;
    int sub  = threadIdx.x & 7;
    int row  = wave * 8 + g;
    if (row >= N) return;
    u32 s = row_ptr[row], e = row_ptr[row + 1];
    // hoist own-row loads so they overlap the gather latency
    uint4 q0 = *(const uint4*)(x0h + (size_t)row * DIM + sub * 8);
    uint4 q1 = *(const uint4*)(x1h + (size_t)row * DIM + sub * 8);
    float acc[8] = {0, 0, 0, 0, 0, 0, 0, 0};
    gather8(x1h, colw, s, e, g, sub, acc);
    float rdeno = 1.0f / fmaxf((float)(e - s), 1.0f);
    const __half2* h0 = (const __half2*)&q0;
    const __half2* h1 = (const __half2*)&q1;
    float r[8];
    #pragma unroll
    for (int k = 0; k < 4; k++) {
        float2 a = __half22float2(h0[k]);
        float2 b = __half22float2(h1[k]);
        float x2a = acc[2 * k] * rdeno;
        float x2b = acc[2 * k + 1] * rdeno;
        x2a = (x2a >= 0.0f) ? x2a : NEG_SLOPE * x2a;
        x2b = (x2b >= 0.0f) ? x2b : NEG_SLOPE * x2b;
        r[2 * k]     = a.x + b.x + x2a;
        r[2 * k + 1] = a.y + b.y + x2b;
    }
    float* op = out + (size_t)row * DIM + sub * 8;
    *(float4*)(op)     = make_float4(r[0], r[1], r[2], r[3]);
    *(float4*)(op + 4) = make_float4(r[4], r[5], r[6], r[7]);
}

static inline size_t align16(size_t x) { return (x + 15) & ~(size_t)15; }

extern "C" void kernel_launch(void* const* d_in, const int* in_sizes, int n_in,
                              void* d_out, int out_size, void* d_ws, size_t ws_size,
                              hipStream_t stream) {
    const int N = in_sizes[0] / DIM;      // 200000
    const int E = in_sizes[1] / 2;        // 600000

    const float* emb = (const float*)d_in[0];
    const int*   ei  = (const int*)d_in[1];
    const float* w   = (const float*)d_in[2];
    float*       out = (float*)d_out;

    const int B     = (N + BKT - 1) / BKT;          // 782 buckets
    const int nblkE = (E + TILEP - 1) / TILEP;      // 293 pair tiles
    const int M     = B * nblkE;                    // 229,126
    const int nb1   = (M + STILE - 1) / STILE;      // 112 (<=128)
    const int rb    = (N + 31) / 32;                // 6250 norm blocks (512 thr)
    const int cvb   = (N + 31) / 32;                // conv blocks: 32 rows/block

    char* ws = (char*)d_ws;
    size_t off = 0;
    __half* x0h    = (__half*)(ws + off); off += align16((size_t)N * DIM * 2);
    __half* x1h    = (__half*)(ws + off); off += align16((size_t)N * DIM * 2);
    u32*    pay    = (u32*)(ws + off);    off += align16((size_t)2 * E * 4);
    u8*     loc8   = (u8*)(ws + off);     off += align16((size_t)2 * E);
    u32*    colw   = (u32*)(ws + off);    off += align16((size_t)2 * E * 4);
    u32*    mat    = (u32*)(ws + off);    off += align16((size_t)M * 4);
    u32*    mscan  = (u32*)(ws + off);    off += align16((size_t)M * 4);
    u32*    row_ptr= (u32*)(ws + off);    off += align16((size_t)(N + 1) * 4);
    u32*    bsum   = (u32*)(ws + off);    off += align16(256 * 4);

    k_norm_hist<<<rb + nblkE, 512, 0, stream>>>(emb, x0h, ei, mat, N, E, rb, B, nblkE);
    k_scan1 <<<nb1, 256, 0, stream>>>(mat, mscan, bsum, M);
    k_place <<<nblkE, 512, 0, stream>>>(ei, w, mscan, bsum, pay, loc8, E, nblkE, B, nb1);
    k_bucket<<<B, 256, 0, stream>>>(pay, loc8, mscan, bsum, row_ptr, colw, N, E, B, nblkE, nb1);

    k_conv1<<<cvb, 256, 0, stream>>>(x0h, row_ptr, colw, x1h, N);
    k_conv2<<<cvb, 256, 0, stream>>>(x0h, x1h, row_ptr, colw, out, N);
}